// Round 2
// baseline (327.616 us; speedup 1.0000x reference)
//
#include <hip/hip_runtime.h>
#include <math.h>

// KWinners2d: x (128,256,32,32) f32, dutyCycle (1,256,1,1) f32
// k = round(0.1 * 256*32*32) = 26214 per batch row.
// 2-streaming-pass structure:
//   pass1: 2048 linear value-bins histogram (uniform occupancy for Gaussian)
//   select1: per-row bin + residual rank
//   pass2 (maskcand): write mask output for decided elements; compact
//           undecided (bin==b1) candidates (~600/row)
//   select2: exact r-th largest among candidates (order-preserving key)
//   fixup: scatter-write winning candidates

#define NB 128
#define NC 256
#define ROW_N 262144            // 256*32*32
#define K_SEL 26214u
#define BINS 2048
#define BPR 16                  // blocks per row for streaming kernels
#define SLICE (ROW_N / BPR)     // 16384
#define NT 256
#define CAND_CAP 16384          // per-row global candidate cap (26x margin)
#define LCAP 2048               // per-block local candidate cap
#define LO_V (-16.0f)
#define SCALE_V 64.0f           // 2048 bins over [-16,16)

// Monotone linear bin; identical code in all kernels (explicit RN ops, no
// contraction ambiguity) so selection and compaction are bit-consistent.
__device__ __forceinline__ int vbin(float bv) {
    float f = __fmul_rn(__fsub_rn(bv, LO_V), SCALE_V);
    int b = (int)f;
    return min(max(b, 0), BINS - 1);
}
__device__ __forceinline__ unsigned int f2key(float f) {
    unsigned int u = __float_as_uint(f);
    return (u & 0x80000000u) ? ~u : (u | 0x80000000u);
}
__device__ __forceinline__ float key2f(unsigned int k) {
    unsigned int u = (k & 0x80000000u) ? (k ^ 0x80000000u) : ~k;
    return __uint_as_float(u);
}

// boost[c] = exp(target_density - duty[c]); fp32 subtract (matches JAX),
// exp in double -> correctly-rounded fp32 (absmax==0 in round 0).
__global__ void boost_kernel(const float* __restrict__ duty, float* __restrict__ boost) {
    const int c = threadIdx.x;
    const float td = 26214.0f / 262144.0f;   // exact in fp32
    float diff = td - duty[c];
    boost[c] = (float)exp((double)diff);
}

// Pass 1: per-row 2048-bin linear histogram of boosted value.
__global__ void __launch_bounds__(NT) hist_kernel(const float* __restrict__ x,
        const float* __restrict__ boost, unsigned int* __restrict__ hist) {
    __shared__ unsigned int h[BINS];
    __shared__ float bl[16];
    const int row = blockIdx.x >> 4;
    const int j = blockIdx.x & 15;
    for (int i = threadIdx.x; i < BINS; i += NT) h[i] = 0u;
    if (threadIdx.x < 16) bl[threadIdx.x] = boost[j * 16 + threadIdx.x];
    __syncthreads();
    const float4* __restrict__ xp =
        (const float4*)(x + (size_t)row * ROW_N + (size_t)j * SLICE);
    const int t = threadIdx.x;
#pragma unroll
    for (int i = 0; i < SLICE / (4 * NT); ++i) {
        const int idx4 = t + i * NT;
        float4 v = xp[idx4];
        const float b = bl[(idx4 * 4) >> 10];   // 4 consecutive elems share channel
        atomicAdd(&h[vbin(__fmul_rn(v.x, b))], 1u);
        atomicAdd(&h[vbin(__fmul_rn(v.y, b))], 1u);
        atomicAdd(&h[vbin(__fmul_rn(v.z, b))], 1u);
        atomicAdd(&h[vbin(__fmul_rn(v.w, b))], 1u);
    }
    __syncthreads();
    unsigned int* __restrict__ gh = hist + (size_t)row * BINS;
    for (int i = threadIdx.x; i < BINS; i += NT)
        if (h[i]) atomicAdd(&gh[i], h[i]);
}

// Per-row: find bin b with S_above(b) < k <= S_above(b)+h[b]; rank within bin.
__global__ void __launch_bounds__(NT) select1_kernel(
        const unsigned int* __restrict__ hist,
        unsigned int* __restrict__ bin_out, unsigned int* __restrict__ k_out) {
    constexpr int PER = BINS / NT;
    const int row = blockIdx.x;
    const unsigned int* __restrict__ h = hist + (size_t)row * BINS;
    const int t = threadIdx.x;
    unsigned int loc[PER];
    unsigned int s = 0;
#pragma unroll
    for (int i = 0; i < PER; ++i) { loc[i] = h[t * PER + i]; s += loc[i]; }
    __shared__ unsigned int suf[NT];
    suf[t] = s;
    __syncthreads();
    for (int off = 1; off < NT; off <<= 1) {
        unsigned int v = (t + off < NT) ? suf[t + off] : 0u;
        __syncthreads();
        suf[t] += v;
        __syncthreads();
    }
    const unsigned int above_chunk = (t + 1 < NT) ? suf[t + 1] : 0u;
    const unsigned int k = K_SEL;
    unsigned int cum = above_chunk;
#pragma unroll
    for (int i = PER - 1; i >= 0; --i) {
        if (k > cum && k <= cum + loc[i]) {
            bin_out[row] = (unsigned int)(t * PER + i);
            k_out[row] = k - cum;
        }
        cum += loc[i];
    }
}

// Pass 2: write decided outputs; compact undecided (bin==b1) candidates.
__global__ void __launch_bounds__(NT) maskcand_kernel(const float* __restrict__ x,
        const float* __restrict__ boost, const unsigned int* __restrict__ bin1,
        unsigned int* __restrict__ cnt, uint2* __restrict__ cand,
        float* __restrict__ out) {
    __shared__ float bl[16];
    __shared__ unsigned int lidx[LCAP];
    __shared__ float lval[LCAP];
    __shared__ unsigned int lcnt, lbase;
    const int row = blockIdx.x >> 4;
    const int j = blockIdx.x & 15;
    if (threadIdx.x == 0) lcnt = 0u;
    if (threadIdx.x < 16) bl[threadIdx.x] = boost[j * 16 + threadIdx.x];
    __syncthreads();
    const int b1 = (int)bin1[row];
    const size_t base = (size_t)row * ROW_N + (size_t)j * SLICE;
    const float4* __restrict__ xp = (const float4*)(x + base);
    float4* __restrict__ op = (float4*)(out + base);
    const int t = threadIdx.x;
#pragma unroll
    for (int i = 0; i < SLICE / (4 * NT); ++i) {
        const int idx4 = t + i * NT;
        float4 v = xp[idx4];
        const float b = bl[(idx4 * 4) >> 10];
        const unsigned int e0 = (unsigned int)(idx4 * 4);
        float4 o;
        {
            int bb = vbin(__fmul_rn(v.x, b));
            o.x = (bb > b1) ? v.x : 0.0f;
            if (bb == b1) { unsigned int p = atomicAdd(&lcnt, 1u);
                            if (p < LCAP) { lidx[p] = e0 + 0u; lval[p] = v.x; } }
        }
        {
            int bb = vbin(__fmul_rn(v.y, b));
            o.y = (bb > b1) ? v.y : 0.0f;
            if (bb == b1) { unsigned int p = atomicAdd(&lcnt, 1u);
                            if (p < LCAP) { lidx[p] = e0 + 1u; lval[p] = v.y; } }
        }
        {
            int bb = vbin(__fmul_rn(v.z, b));
            o.z = (bb > b1) ? v.z : 0.0f;
            if (bb == b1) { unsigned int p = atomicAdd(&lcnt, 1u);
                            if (p < LCAP) { lidx[p] = e0 + 2u; lval[p] = v.z; } }
        }
        {
            int bb = vbin(__fmul_rn(v.w, b));
            o.w = (bb > b1) ? v.w : 0.0f;
            if (bb == b1) { unsigned int p = atomicAdd(&lcnt, 1u);
                            if (p < LCAP) { lidx[p] = e0 + 3u; lval[p] = v.w; } }
        }
        op[idx4] = o;
    }
    __syncthreads();
    const unsigned int m = min(lcnt, (unsigned int)LCAP);
    if (threadIdx.x == 0) lbase = atomicAdd(&cnt[row], m);
    __syncthreads();
    const unsigned int gb = lbase;
    uint2* __restrict__ cr = cand + (size_t)row * CAND_CAP;
    const unsigned int joff = (unsigned int)(j * SLICE);
    for (unsigned int i = threadIdx.x; i < m; i += NT) {
        unsigned int p = gb + i;
        if (p < CAND_CAP)
            cr[p] = make_uint2(lidx[i] + joff, __float_as_uint(lval[i]));
    }
}

// Per-row exact selection: r-th largest boosted value among candidates.
__global__ void __launch_bounds__(NT) select2_kernel(
        const unsigned int* __restrict__ cnt, const uint2* __restrict__ cand,
        const float* __restrict__ boost, const unsigned int* __restrict__ k1,
        float* __restrict__ thresh) {
    __shared__ unsigned int keys[CAND_CAP];
    __shared__ float bl[NC];
    __shared__ unsigned int result;
    const int row = blockIdx.x;
    const int t = threadIdx.x;
    bl[t] = boost[t];
    const unsigned int c = min(cnt[row], (unsigned int)CAND_CAP);
    const uint2* __restrict__ cr = cand + (size_t)row * CAND_CAP;
    __syncthreads();
    for (unsigned int i = t; i < c; i += NT) {
        uint2 e = cr[i];
        float bv = __fmul_rn(__uint_as_float(e.y), bl[(e.x >> 10) & 255u]);
        keys[i] = f2key(bv);
    }
    __syncthreads();
    const unsigned int r = k1[row];
    for (unsigned int i = t; i < c; i += NT) {
        const unsigned int kk = keys[i];
        unsigned int g = 0, eq = 0;
        for (unsigned int jj = 0; jj < c; ++jj) {   // uniform j -> LDS broadcast
            unsigned int q = keys[jj];
            g += (q > kk);
            eq += (q == kk);
        }
        if (g < r && r <= g + eq) result = kk;
    }
    __syncthreads();
    if (t == 0) thresh[row] = key2f(result);
}

// Scatter-write winning candidates (bv >= thresh).
__global__ void __launch_bounds__(NT) fixup_kernel(
        const unsigned int* __restrict__ cnt, const uint2* __restrict__ cand,
        const float* __restrict__ boost, const float* __restrict__ thresh,
        float* __restrict__ out) {
    const int row = blockIdx.x;
    const unsigned int c = min(cnt[row], (unsigned int)CAND_CAP);
    const float tf = thresh[row];
    const uint2* __restrict__ cr = cand + (size_t)row * CAND_CAP;
    for (unsigned int i = threadIdx.x; i < c; i += NT) {
        uint2 e = cr[i];
        float val = __uint_as_float(e.y);
        float bv = __fmul_rn(val, boost[(e.x >> 10) & 255u]);
        if (bv >= tf) out[(size_t)row * ROW_N + e.x] = val;
    }
}

extern "C" void kernel_launch(void* const* d_in, const int* in_sizes, int n_in,
                              void* d_out, int out_size, void* d_ws, size_t ws_size,
                              hipStream_t stream) {
    const float* x = (const float*)d_in[0];
    const float* duty = (const float*)d_in[1];
    float* out = (float*)d_out;
    char* ws = (char*)d_ws;

    float* boost        = (float*)ws;                         // 1 KB
    unsigned int* bin1  = (unsigned int*)(ws + 1024);         // 512 B
    unsigned int* k1    = (unsigned int*)(ws + 1536);         // 512 B
    float* thresh       = (float*)(ws + 2048);                // 512 B
    unsigned int* cnt   = (unsigned int*)(ws + 2560);         // 512 B
    unsigned int* hist  = (unsigned int*)(ws + 4096);         // 128*2048*4 = 1 MB
    uint2* cand         = (uint2*)(ws + 4096 + (size_t)NB * BINS * 4);  // 16 MB

    // zero cnt + hist in one fill
    hipMemsetAsync(ws + 2560, 0, (4096 - 2560) + (size_t)NB * BINS * 4, stream);

    boost_kernel<<<1, NC, 0, stream>>>(duty, boost);
    hist_kernel<<<NB * BPR, NT, 0, stream>>>(x, boost, hist);
    select1_kernel<<<NB, NT, 0, stream>>>(hist, bin1, k1);
    maskcand_kernel<<<NB * BPR, NT, 0, stream>>>(x, boost, bin1, cnt, cand, out);
    select2_kernel<<<NB, NT, 0, stream>>>(cnt, cand, boost, k1, thresh);
    fixup_kernel<<<NB, NT, 0, stream>>>(cnt, cand, boost, thresh, out);
}

// Round 5
// 298.110 us; speedup vs baseline: 1.0990x; 1.0990x over previous
//
#include <hip/hip_runtime.h>
#include <math.h>

// KWinners2d: x (128,256,32,32) f32, dutyCycle (1,256,1,1) f32
// k = round(0.1 * 256*32*32) = 26214 per batch row.
// 2-streaming-pass structure, zero global atomics, 4 kernels:
//   hist:     per-block private 2048-bin linear histogram -> disjoint slices
//   select1:  sum 16 slices, per-row bin b1 + residual rank r
//   maskcand: write decided outputs (nontemporal); compact bin==b1 candidates
//             into fixed per-block regions with exact counts
//   select2:  exact 3-pass LDS radix-select among candidates + fused fixup

#define NB 128
#define NC 256
#define ROW_N 262144            // 256*32*32
#define K_SEL 26214u
#define BINS 2048
#define BPR 16                  // blocks per row for streaming kernels
#define SLICE (ROW_N / BPR)     // 16384
#define NT 256
#define LCAP 1024               // per-block candidate cap (avg ~64)
#define CAND_CAP (BPR * LCAP)   // 16384 per row
#define LO_V (-16.0f)
#define SCALE_V 64.0f           // 2048 bins over [-16,16)

typedef float nfloat4 __attribute__((ext_vector_type(4)));  // native vec for nt-store

// Monotone linear bin; identical code in all kernels (explicit RN ops) so
// selection and compaction are bit-consistent across kernels.
__device__ __forceinline__ int vbin(float bv) {
    float f = __fmul_rn(__fsub_rn(bv, LO_V), SCALE_V);
    int b = (int)f;
    return min(max(b, 0), BINS - 1);
}
__device__ __forceinline__ unsigned int f2key(float f) {
    unsigned int u = __float_as_uint(f);
    return (u & 0x80000000u) ? ~u : (u | 0x80000000u);
}
__device__ __forceinline__ float key2f(unsigned int k) {
    unsigned int u = (k & 0x80000000u) ? (k ^ 0x80000000u) : ~k;
    return __uint_as_float(u);
}
// boost = exp(td - duty) : fp32 subtract (matches JAX), exp in double ->
// correctly-rounded fp32; deterministic, so per-kernel recompute is
// bit-identical (absmax==0 in rounds 0-2 with this formula).
__device__ __forceinline__ float boost_of(float d) {
    const float td = 26214.0f / 262144.0f;   // exact in fp32
    float diff = td - d;
    return (float)exp((double)diff);
}

// Pass 1: per-block 2048-bin histogram, stored to its own slice (no atomics).
__global__ void __launch_bounds__(NT) hist_kernel(const float* __restrict__ x,
        const float* __restrict__ duty, unsigned int* __restrict__ hist) {
    __shared__ unsigned int h[BINS];
    __shared__ float bl[16];
    const int row = blockIdx.x >> 4;
    const int j = blockIdx.x & 15;
    for (int i = threadIdx.x; i < BINS; i += NT) h[i] = 0u;
    if (threadIdx.x < 16) bl[threadIdx.x] = boost_of(duty[j * 16 + threadIdx.x]);
    __syncthreads();
    const float4* __restrict__ xp =
        (const float4*)(x + (size_t)row * ROW_N + (size_t)j * SLICE);
    const int t = threadIdx.x;
#pragma unroll
    for (int i = 0; i < SLICE / (4 * NT); ++i) {
        const int idx4 = t + i * NT;
        float4 v = xp[idx4];
        const float b = bl[(idx4 * 4) >> 10];   // 4 consecutive elems share channel
        atomicAdd(&h[vbin(__fmul_rn(v.x, b))], 1u);
        atomicAdd(&h[vbin(__fmul_rn(v.y, b))], 1u);
        atomicAdd(&h[vbin(__fmul_rn(v.z, b))], 1u);
        atomicAdd(&h[vbin(__fmul_rn(v.w, b))], 1u);
    }
    __syncthreads();
    unsigned int* __restrict__ gh = hist + (size_t)blockIdx.x * BINS;
    for (int i = threadIdx.x; i < BINS; i += NT) gh[i] = h[i];
}

// Per-row: sum 16 slices, then find bin b1 with S_above < k <= S_above+h[b1].
__global__ void __launch_bounds__(NT) select1_kernel(
        const unsigned int* __restrict__ hist,
        unsigned int* __restrict__ bin_out, unsigned int* __restrict__ k_out) {
    __shared__ unsigned int hs[BINS];
    __shared__ unsigned int suf[NT];
    const int row = blockIdx.x;
    const int t = threadIdx.x;
    const unsigned int* __restrict__ gh = hist + (size_t)row * BPR * BINS;
    for (int bin = t; bin < BINS; bin += NT) {
        unsigned int s = 0;
#pragma unroll
        for (int j = 0; j < BPR; ++j) s += gh[j * BINS + bin];
        hs[bin] = s;
    }
    __syncthreads();
    constexpr int PER = BINS / NT;
    unsigned int loc[PER];
    unsigned int s = 0;
#pragma unroll
    for (int i = 0; i < PER; ++i) { loc[i] = hs[t * PER + i]; s += loc[i]; }
    suf[t] = s;
    __syncthreads();
    for (int off = 1; off < NT; off <<= 1) {
        unsigned int v = (t + off < NT) ? suf[t + off] : 0u;
        __syncthreads();
        suf[t] += v;
        __syncthreads();
    }
    unsigned int cum = (t + 1 < NT) ? suf[t + 1] : 0u;   // strictly-above count
    const unsigned int k = K_SEL;
#pragma unroll
    for (int i = PER - 1; i >= 0; --i) {
        if (k > cum && k <= cum + loc[i]) {
            bin_out[row] = (unsigned int)(t * PER + i);
            k_out[row] = k - cum;
        }
        cum += loc[i];
    }
}

// Pass 2: write decided outputs (nontemporal, keep x L3-resident); compact
// undecided (bin==b1) candidates into fixed per-block region, exact count.
__global__ void __launch_bounds__(NT) maskcand_kernel(const float* __restrict__ x,
        const float* __restrict__ duty, const unsigned int* __restrict__ bin1,
        unsigned int* __restrict__ ccnt, uint2* __restrict__ cand,
        float* __restrict__ out) {
    __shared__ float bl[16];
    __shared__ unsigned int lidx[LCAP];
    __shared__ float lval[LCAP];
    __shared__ unsigned int lcnt;
    const int row = blockIdx.x >> 4;
    const int j = blockIdx.x & 15;
    if (threadIdx.x == 0) lcnt = 0u;
    if (threadIdx.x < 16) bl[threadIdx.x] = boost_of(duty[j * 16 + threadIdx.x]);
    __syncthreads();
    const int b1 = (int)bin1[row];
    const size_t base = (size_t)row * ROW_N + (size_t)j * SLICE;
    const float4* __restrict__ xp = (const float4*)(x + base);
    nfloat4* __restrict__ op = (nfloat4*)(out + base);
    const int t = threadIdx.x;
#pragma unroll
    for (int i = 0; i < SLICE / (4 * NT); ++i) {
        const int idx4 = t + i * NT;
        float4 v = xp[idx4];
        const float b = bl[(idx4 * 4) >> 10];
        const unsigned int e0 = (unsigned int)(idx4 * 4);
        nfloat4 o;
        {
            int bb = vbin(__fmul_rn(v.x, b));
            o.x = (bb > b1) ? v.x : 0.0f;
            if (bb == b1) { unsigned int p = atomicAdd(&lcnt, 1u);
                            if (p < LCAP) { lidx[p] = e0 + 0u; lval[p] = v.x; } }
        }
        {
            int bb = vbin(__fmul_rn(v.y, b));
            o.y = (bb > b1) ? v.y : 0.0f;
            if (bb == b1) { unsigned int p = atomicAdd(&lcnt, 1u);
                            if (p < LCAP) { lidx[p] = e0 + 1u; lval[p] = v.y; } }
        }
        {
            int bb = vbin(__fmul_rn(v.z, b));
            o.z = (bb > b1) ? v.z : 0.0f;
            if (bb == b1) { unsigned int p = atomicAdd(&lcnt, 1u);
                            if (p < LCAP) { lidx[p] = e0 + 2u; lval[p] = v.z; } }
        }
        {
            int bb = vbin(__fmul_rn(v.w, b));
            o.w = (bb > b1) ? v.w : 0.0f;
            if (bb == b1) { unsigned int p = atomicAdd(&lcnt, 1u);
                            if (p < LCAP) { lidx[p] = e0 + 3u; lval[p] = v.w; } }
        }
        __builtin_nontemporal_store(o, &op[idx4]);
    }
    __syncthreads();
    const unsigned int m = min(lcnt, (unsigned int)LCAP);
    if (t == 0) ccnt[blockIdx.x] = m;
    uint2* __restrict__ cr = cand + (size_t)row * CAND_CAP + (size_t)j * LCAP;
    const unsigned int joff = (unsigned int)(j * SLICE);
    for (unsigned int i = t; i < m; i += NT)
        cr[i] = make_uint2(lidx[i] + joff, __float_as_uint(lval[i]));
}

// One radix pass: among keys with (key & pmask)==pval, histogram
// (key>>shift)&(NBINS-1), find bin containing (descending) rank res[1];
// writes res[0]=bin, res[1]=residual rank. All threads participate.
template <int NBINS>
__device__ void radix_pass(const unsigned int* __restrict__ keys, unsigned int c,
        unsigned int pmask, unsigned int pval, int shift,
        unsigned int* h, unsigned int* suf, unsigned int* res) {
    const int t = threadIdx.x;
    const unsigned int r = res[1];          // read before any writer (sync below)
    for (int i = t; i < NBINS; i += NT) h[i] = 0u;
    __syncthreads();
    for (unsigned int i = t; i < c; i += NT) {
        unsigned int k = keys[i];
        if ((k & pmask) == pval)
            atomicAdd(&h[(k >> shift) & (unsigned int)(NBINS - 1)], 1u);
    }
    __syncthreads();
    constexpr int PER = NBINS / NT;
    unsigned int loc[PER];
    unsigned int s = 0;
#pragma unroll
    for (int i = 0; i < PER; ++i) { loc[i] = h[t * PER + i]; s += loc[i]; }
    suf[t] = s;
    __syncthreads();
    for (int off = 1; off < NT; off <<= 1) {
        unsigned int v = (t + off < NT) ? suf[t + off] : 0u;
        __syncthreads();
        suf[t] += v;
        __syncthreads();
    }
    unsigned int cum = (t + 1 < NT) ? suf[t + 1] : 0u;
#pragma unroll
    for (int i = PER - 1; i >= 0; --i) {
        if (r > cum && r <= cum + loc[i]) {
            res[0] = (unsigned int)(t * PER + i);
            res[1] = r - cum;
        }
        cum += loc[i];
    }
    __syncthreads();
}

// Exact r-th largest among candidates via 3-pass radix on order-preserving
// keys; fused fixup scatter (bv >= thresh, float compare like reference).
__global__ void __launch_bounds__(NT) select2_kernel(const float* __restrict__ duty,
        const unsigned int* __restrict__ ccnt, const uint2* __restrict__ cand,
        const unsigned int* __restrict__ k1, float* __restrict__ out) {
    __shared__ unsigned int keys[CAND_CAP];   // 64 KB
    __shared__ unsigned int h[BINS];          // 8 KB
    __shared__ unsigned int suf[NT];
    __shared__ unsigned int res[2];
    __shared__ float bl[NC];
    __shared__ unsigned int cb[BPR + 1];
    const int row = blockIdx.x;
    const int t = threadIdx.x;
    bl[t] = boost_of(duty[t]);                // NT == NC
    if (t == 0) {
        unsigned int acc = 0;
        for (int j = 0; j < BPR; ++j) { cb[j] = acc; acc += ccnt[row * BPR + j]; }
        cb[BPR] = acc;
        res[1] = k1[row];
    }
    __syncthreads();
    const unsigned int c = cb[BPR];
    const uint2* __restrict__ cr = cand + (size_t)row * CAND_CAP;
    for (int j = 0; j < BPR; ++j) {
        const unsigned int cj = cb[j + 1] - cb[j];
        const unsigned int b0 = cb[j];
        for (unsigned int i = t; i < cj; i += NT) {
            uint2 e = cr[j * LCAP + i];
            float bv = __fmul_rn(__uint_as_float(e.y), bl[e.x >> 10]);
            keys[b0 + i] = f2key(bv);
        }
    }
    __syncthreads();
    radix_pass<2048>(keys, c, 0u, 0u, 21, h, suf, res);
    const unsigned int b1 = res[0];
    radix_pass<2048>(keys, c, 0xFFE00000u, b1 << 21, 10, h, suf, res);
    const unsigned int b2 = res[0];
    radix_pass<1024>(keys, c, 0xFFFFFC00u, (b1 << 21) | (b2 << 10), 0, h, suf, res);
    const unsigned int b3 = res[0];
    const float tf = key2f((b1 << 21) | (b2 << 10) | b3);
    float* __restrict__ orow = out + (size_t)row * ROW_N;
    for (int j = 0; j < BPR; ++j) {
        const unsigned int cj = cb[j + 1] - cb[j];
        for (unsigned int i = t; i < cj; i += NT) {
            uint2 e = cr[j * LCAP + i];
            float val = __uint_as_float(e.y);
            float bv = __fmul_rn(val, bl[e.x >> 10]);
            if (bv >= tf) orow[e.x] = val;
        }
    }
}

extern "C" void kernel_launch(void* const* d_in, const int* in_sizes, int n_in,
                              void* d_out, int out_size, void* d_ws, size_t ws_size,
                              hipStream_t stream) {
    const float* x = (const float*)d_in[0];
    const float* duty = (const float*)d_in[1];
    float* out = (float*)d_out;
    char* ws = (char*)d_ws;

    unsigned int* bin1 = (unsigned int*)(ws);              // 512 B
    unsigned int* k1   = (unsigned int*)(ws + 512);        // 512 B
    unsigned int* ccnt = (unsigned int*)(ws + 4096);       // 2048*4 = 8 KB
    unsigned int* hist = (unsigned int*)(ws + 16384);      // 2048*2048*4 = 16 MB
    uint2* cand = (uint2*)(ws + 16384 + (size_t)NB * BPR * BINS * 4);  // 16 MB

    hist_kernel<<<NB * BPR, NT, 0, stream>>>(x, duty, hist);
    select1_kernel<<<NB, NT, 0, stream>>>(hist, bin1, k1);
    maskcand_kernel<<<NB * BPR, NT, 0, stream>>>(x, duty, bin1, ccnt, cand, out);
    select2_kernel<<<NB, NT, 0, stream>>>(duty, ccnt, cand, k1, out);
}